// Round 19
// baseline (678.374 us; speedup 1.0000x reference)
//
#include <hip/hip_runtime.h>
#include <math.h>

#define D 64
#define NB_SCAN 256

typedef unsigned short ushort_t;
typedef __attribute__((ext_vector_type(8))) short bf16x8;
typedef __attribute__((ext_vector_type(4))) float f32x4;

__device__ __forceinline__ ushort_t f2bf(float f) {
  unsigned int u = __float_as_uint(f);
  unsigned int r = (u + 0x7fffu + ((u >> 16) & 1u)) >> 16;  // RNE
  return (ushort_t)r;
}

__device__ __forceinline__ float bf2f(ushort_t b) {
  return __uint_as_float((unsigned int)b << 16);
}

// ---------------- degree histogram (int) ----------------
__global__ void hist_kernel(const int* __restrict__ dst, int* __restrict__ hist, int E) {
  int i = blockIdx.x * blockDim.x + threadIdx.x;
  int stride = gridDim.x * blockDim.x;
  for (int e = i; e < E; e += stride) atomicAdd(&hist[dst[e]], 1);
}

// ---------------- 3-pass scan ----------------
__global__ void scanA_kernel(const int* __restrict__ hist, int* __restrict__ blocksum, int N) {
  __shared__ int red[256];
  int b = blockIdx.x, t = threadIdx.x;
  int chunk = (N + NB_SCAN - 1) / NB_SCAN;
  int beg = b * chunk;
  int end = min(beg + chunk, N);
  int s = 0;
  for (int i = beg + t; i < end; i += 256) s += hist[i];
  red[t] = s;
  __syncthreads();
  for (int off = 128; off > 0; off >>= 1) {
    if (t < off) red[t] += red[t + off];
    __syncthreads();
  }
  if (t == 0) blocksum[b] = red[0];
}

__global__ void scanB_kernel(const int* __restrict__ blocksum, int* __restrict__ blockoff,
                             int* __restrict__ rowptr_last) {
  __shared__ int sm[NB_SCAN];
  int t = threadIdx.x;
  sm[t] = blocksum[t];
  __syncthreads();
  for (int off = 1; off < NB_SCAN; off <<= 1) {
    int v = (t >= off) ? sm[t - off] : 0;
    __syncthreads();
    sm[t] += v;
    __syncthreads();
  }
  blockoff[t] = (t == 0) ? 0 : sm[t - 1];
  if (t == NB_SCAN - 1) rowptr_last[0] = sm[t];
}

// scanC also zeroes hist (it becomes the fill cursor) — saves a memset pass.
__global__ void scanC_kernel(int* __restrict__ hist, const int* __restrict__ blockoff,
                             int* __restrict__ rowptr, float* __restrict__ degf, int N) {
  __shared__ int sm[256];
  int b = blockIdx.x, t = threadIdx.x;
  int chunk = (N + NB_SCAN - 1) / NB_SCAN;
  int beg = b * chunk;
  int end = min(beg + chunk, N);
  int sub = (chunk + 255) / 256;
  int mybeg = beg + t * sub;
  int myend = min(mybeg + sub, end);
  int s = 0;
  for (int i = mybeg; i < myend; ++i) s += hist[i];
  sm[t] = s;
  __syncthreads();
  for (int off = 1; off < 256; off <<= 1) {
    int v = (t >= off) ? sm[t - off] : 0;
    __syncthreads();
    sm[t] += v;
    __syncthreads();
  }
  int run = blockoff[b] + ((t == 0) ? 0 : sm[t - 1]);
  for (int i = mybeg; i < myend; ++i) {
    int h = hist[i];
    hist[i] = 0;  // reset cursor in-pass
    rowptr[i] = run;
    degf[i] = (float)h;
    run += h;
  }
}

// ---------------- range-partitioned XCD-affine CSR fill ----------------
__global__ void fillp_kernel(const int* __restrict__ src, const int* __restrict__ dst,
                             const int* __restrict__ rowptr, int* __restrict__ cursor,
                             int* __restrict__ csr_src, int E, int N) {
  int r = blockIdx.x & 7;
  int c = blockIdx.x >> 3;
  int nchunk = gridDim.x >> 3;
  int lo = (r * N) >> 3;
  int hi = ((r + 1) * N) >> 3;
  int per = (E + nchunk - 1) / nchunk;
  int beg = c * per;
  int end = min(beg + per, E);
  for (int e = beg + (int)threadIdx.x; e < end; e += (int)blockDim.x) {
    int d = dst[e];
    if (d >= lo && d < hi) {
      int pos = atomicAdd(&cursor[d], 1);
      csr_src[rowptr[d] + pos] = src[e];
    }
  }
}

// ---------------- f32 -> bf16 convert (vectorized) ----------------
__global__ void cvt_kernel(const float* __restrict__ in, ushort_t* __restrict__ outb, int total4) {
  int i = blockIdx.x * blockDim.x + threadIdx.x;
  int stride = gridDim.x * blockDim.x;
  const float4* in4 = (const float4*)in;
  for (int idx = i; idx < total4; idx += stride) {
    float4 v = in4[idx];
    ushort4 u;
    u.x = f2bf(v.x); u.y = f2bf(v.y); u.z = f2bf(v.z); u.w = f2bf(v.w);
    ((ushort4*)outb)[idx] = u;
  }
}

// ---------------- pack ALL 7 weights in one launch: 112 blocks, b>>4 selects matrix ----------------
__global__ void packw7_kernel(const float* __restrict__ W0, const float* __restrict__ Wl,
                              const float* __restrict__ Wr, const float* __restrict__ W2a,
                              const float* __restrict__ W2b, const float* __restrict__ Wrel,
                              const float* __restrict__ Wroot, ushort_t* __restrict__ WpBase) {
  int m = blockIdx.x >> 4;                 // matrix id 0..6
  int idx = (blockIdx.x & 15) * 256 + threadIdx.x;  // 0..4095
  const float* W;
  switch (m) {
    case 0: W = W0; break;
    case 1: W = Wl; break;
    case 2: W = Wr; break;
    case 3: W = W2a; break;
    case 4: W = W2b; break;
    case 5: W = Wrel; break;
    default: W = Wroot; break;
  }
  ushort_t* Wp = WpBase + (size_t)m * 4096;
  int i = idx & 7;
  int lane = (idx >> 3) & 63;
  int ct = (idx >> 9) & 3;
  int kt = idx >> 11;
  int k = kt * 32 + ((lane >> 4) << 3) + i;
  int c = (ct << 4) + (lane & 15);
  Wp[idx] = f2bf(W[k * D + c]);
}

// ------- bf16 gather-sum -> bf16 agg: uint4 loads, 8 edges/step (lane = e8*8 + c8) -------
#define ACC8(p) { \
  a0 += __uint_as_float(p.x << 16); a1 += __uint_as_float(p.x & 0xffff0000u); \
  a2 += __uint_as_float(p.y << 16); a3 += __uint_as_float(p.y & 0xffff0000u); \
  a4 += __uint_as_float(p.z << 16); a5 += __uint_as_float(p.z & 0xffff0000u); \
  a6 += __uint_as_float(p.w << 16); a7 += __uint_as_float(p.w & 0xffff0000u); }

#define GSTEP8(j) { int i0 = 8 * (j) + e8; \
  int ia = __shfl(myidx, i0 & 63); \
  uint4 p = *(const uint4*)(hb + (size_t)ia * D + (c8 << 3)); \
  if (i0 >= cnt) { p.x = 0u; p.y = 0u; p.z = 0u; p.w = 0u; } \
  ACC8(p) }

__global__ void gatherb_kernel(const ushort_t* __restrict__ hb, const int* __restrict__ rowptr,
                               const int* __restrict__ csr_src, ushort_t* __restrict__ aggb, int N) {
  int lane = threadIdx.x & 63;
  int wid = (blockIdx.x * blockDim.x + threadIdx.x) >> 6;
  int nw = (gridDim.x * blockDim.x) >> 6;
  int e8 = lane >> 3;
  int c8 = lane & 7;
  for (int n = wid; n < N; n += nw) {
    int beg = __builtin_amdgcn_readfirstlane(rowptr[n]);
    int end = __builtin_amdgcn_readfirstlane(rowptr[n + 1]);
    int cnt = end - beg;
    float a0 = 0.f, a1 = 0.f, a2 = 0.f, a3 = 0.f, a4 = 0.f, a5 = 0.f, a6 = 0.f, a7 = 0.f;
    if (cnt <= 64) {
      int myidx = (lane < cnt) ? csr_src[beg + lane] : 0;
      if (cnt <= 16) {
        GSTEP8(0) GSTEP8(1)
      } else if (cnt <= 32) {
        GSTEP8(0) GSTEP8(1) GSTEP8(2) GSTEP8(3)
      } else {
        GSTEP8(0) GSTEP8(1) GSTEP8(2) GSTEP8(3)
        GSTEP8(4) GSTEP8(5) GSTEP8(6) GSTEP8(7)
      }
    } else {
      for (int k = beg; k < end; k += 64) {
        int myidx = (k + lane < end) ? csr_src[k + lane] : 0;
        int cnt2 = end - k; if (cnt2 > 64) cnt2 = 64;
        int cnt = cnt2;
#pragma unroll
        for (int j = 0; j < 8; ++j) {
          if (8 * j < cnt) { GSTEP8(j) }
        }
      }
    }
    a0 += __shfl_xor(a0, 8); a0 += __shfl_xor(a0, 16); a0 += __shfl_xor(a0, 32);
    a1 += __shfl_xor(a1, 8); a1 += __shfl_xor(a1, 16); a1 += __shfl_xor(a1, 32);
    a2 += __shfl_xor(a2, 8); a2 += __shfl_xor(a2, 16); a2 += __shfl_xor(a2, 32);
    a3 += __shfl_xor(a3, 8); a3 += __shfl_xor(a3, 16); a3 += __shfl_xor(a3, 32);
    a4 += __shfl_xor(a4, 8); a4 += __shfl_xor(a4, 16); a4 += __shfl_xor(a4, 32);
    a5 += __shfl_xor(a5, 8); a5 += __shfl_xor(a5, 16); a5 += __shfl_xor(a5, 32);
    a6 += __shfl_xor(a6, 8); a6 += __shfl_xor(a6, 16); a6 += __shfl_xor(a6, 32);
    a7 += __shfl_xor(a7, 8); a7 += __shfl_xor(a7, 16); a7 += __shfl_xor(a7, 32);
    if (lane < 8) {
      uint4 u;
      u.x = ((unsigned int)f2bf(a1) << 16) | (unsigned int)f2bf(a0);
      u.y = ((unsigned int)f2bf(a3) << 16) | (unsigned int)f2bf(a2);
      u.z = ((unsigned int)f2bf(a5) << 16) | (unsigned int)f2bf(a4);
      u.w = ((unsigned int)f2bf(a7) << 16) | (unsigned int)f2bf(a6);
      *(uint4*)(aggb + (size_t)n * D + (c8 << 3)) = u;
    }
  }
}

// ======== MFMA matmul: out = A1@W1 (scaled) [+ A2@W2] + bias(masked) ========
template <int DUAL, int SCALEA, int MASKB, int RELU, int STATS, int OUTBF>
__global__ __launch_bounds__(256, 4)
void mmx_kernel(const ushort_t* __restrict__ A1, const ushort_t* __restrict__ A2,
                const ushort_t* __restrict__ Wp1, const ushort_t* __restrict__ Wp2,
                const float* __restrict__ bias, const float* __restrict__ deg,
                float* __restrict__ outf, ushort_t* __restrict__ outb,
                float* __restrict__ stats, int N) {
  int lane = threadIdx.x & 63;
  int wv = (blockIdx.x * blockDim.x + threadIdx.x) >> 6;
  int nw = (gridDim.x * blockDim.x) >> 6;
  int T = (N + 15) >> 4;
  int lr = lane & 15;
  int lk = lane >> 4;
  float s1[4] = {0.f, 0.f, 0.f, 0.f};
  float s2[4] = {0.f, 0.f, 0.f, 0.f};

  for (int t = wv; t < T; t += nw) {
    int r0 = t << 4;
    int rowA = r0 + lr;
    if (rowA >= N) rowA = N - 1;
    const ushort_t* pa = A1 + (size_t)rowA * D + (lk << 3);
    bf16x8 a1k0 = *(const bf16x8*)(pa);
    bf16x8 a1k1 = *(const bf16x8*)(pa + 32);
    bf16x8 a2k0{}, a2k1{};
    if constexpr (DUAL) {
      const ushort_t* ph = A2 + (size_t)rowA * D + (lk << 3);
      a2k0 = *(const bf16x8*)(ph);
      a2k1 = *(const bf16x8*)(ph + 32);
    }
    float invd[4], msk[4];
#pragma unroll
    for (int rg = 0; rg < 4; ++rg) {
      if constexpr (SCALEA || MASKB) {
        int rr = r0 + (lk << 2) + rg;
        if (rr >= N) rr = N - 1;
        float dv = deg[rr];
        invd[rg] = 1.0f / fmaxf(dv, 1.0f);
        msk[rg] = (dv > 0.f) ? 1.f : 0.f;
      } else {
        invd[rg] = 1.f; msk[rg] = 1.f;
      }
    }

#pragma unroll
    for (int ct = 0; ct < 4; ++ct) {
      bf16x8 w1k0 = *(const bf16x8*)(Wp1 + (((0 * 4 + ct) * 64 + lane) << 3));
      bf16x8 w1k1 = *(const bf16x8*)(Wp1 + (((1 * 4 + ct) * 64 + lane) << 3));
      f32x4 accA = {0.f, 0.f, 0.f, 0.f};
      accA = __builtin_amdgcn_mfma_f32_16x16x32_bf16(a1k0, w1k0, accA, 0, 0, 0);
      accA = __builtin_amdgcn_mfma_f32_16x16x32_bf16(a1k1, w1k1, accA, 0, 0, 0);
      f32x4 accH = {0.f, 0.f, 0.f, 0.f};
      if constexpr (DUAL) {
        bf16x8 w2k0 = *(const bf16x8*)(Wp2 + (((0 * 4 + ct) * 64 + lane) << 3));
        bf16x8 w2k1 = *(const bf16x8*)(Wp2 + (((1 * 4 + ct) * 64 + lane) << 3));
        accH = __builtin_amdgcn_mfma_f32_16x16x32_bf16(a2k0, w2k0, accH, 0, 0, 0);
        accH = __builtin_amdgcn_mfma_f32_16x16x32_bf16(a2k1, w2k1, accH, 0, 0, 0);
      }
      float bj = bias[(ct << 4) + lr];
#pragma unroll
      for (int rg = 0; rg < 4; ++rg) {
        int row = r0 + (lk << 2) + rg;
        float v = accA[rg];
        if constexpr (SCALEA) v *= invd[rg];
        if constexpr (DUAL) v += accH[rg];
        if constexpr (MASKB) v += bj * msk[rg]; else v += bj;
        if constexpr (RELU) v = fmaxf(v, 0.f);
        if (row < N) {
          int col = (ct << 4) + lr;
          if constexpr (OUTBF) outb[(size_t)row * D + col] = f2bf(v);
          else outf[(size_t)row * D + col] = v;
          if constexpr (STATS) { s1[ct] += v; s2[ct] += v * v; }
        }
      }
    }
  }

  if constexpr (STATS) {
    __shared__ float red[2][4][256];
#pragma unroll
    for (int ct = 0; ct < 4; ++ct) {
      red[0][ct][threadIdx.x] = s1[ct];
      red[1][ct][threadIdx.x] = s2[ct];
    }
    __syncthreads();
    int tt = threadIdx.x;
    if (tt < 64) {
      int ct = tt >> 4, base = tt & 15;
      float t1 = 0.f, t2 = 0.f;
      for (int i = 0; i < 16; ++i) {
        t1 += red[0][ct][base + i * 16];
        t2 += red[1][ct][base + i * 16];
      }
      atomicAdd(&stats[tt], t1);
      atomicAdd(&stats[D + tt], t2);
    }
  }
}

// ---------------- BN apply + ELU (bn_coef fused in-block): bf16 h_pre -> bf16 hb ----------------
__global__ void apply_kernel(const ushort_t* __restrict__ hpre, const float* __restrict__ stats,
                             const float* __restrict__ gamma, const float* __restrict__ beta,
                             float invN, ushort_t* __restrict__ hb, int total4) {
  __shared__ float cf[128];
  int t = threadIdx.x;
  if (t < 64) {
    float mu = stats[t] * invN;
    float var = fmaxf(stats[D + t] * invN - mu * mu, 0.f);
    float rs = rsqrtf(var + 1e-5f);
    float sc = gamma[t] * rs;
    cf[t] = sc;
    cf[64 + t] = beta[t] - mu * sc;
  }
  __syncthreads();
  int i = blockIdx.x * blockDim.x + t;
  int stride = gridDim.x * blockDim.x;
  const ushort4* in4 = (const ushort4*)hpre;
  for (int idx = i; idx < total4; idx += stride) {
    int col4 = idx & 15;
    float4 sc = *(const float4*)(cf + col4 * 4);
    float4 sh = *(const float4*)(cf + 64 + col4 * 4);
    ushort4 vu = in4[idx];
    float4 r;
    r.x = bf2f(vu.x) * sc.x + sh.x;
    r.y = bf2f(vu.y) * sc.y + sh.y;
    r.z = bf2f(vu.z) * sc.z + sh.z;
    r.w = bf2f(vu.w) * sc.w + sh.w;
    r.x = r.x > 0.f ? r.x : __expf(r.x) - 1.f;
    r.y = r.y > 0.f ? r.y : __expf(r.y) - 1.f;
    r.z = r.z > 0.f ? r.z : __expf(r.z) - 1.f;
    r.w = r.w > 0.f ? r.w : __expf(r.w) - 1.f;
    ushort4 u;
    u.x = f2bf(r.x); u.y = f2bf(r.y); u.z = f2bf(r.z); u.w = f2bf(r.w);
    ((ushort4*)hb)[idx] = u;
  }
}

// ---------------- global mean pool with fused BN+ELU (reads bf16 h_pre) ----------------
__global__ void poolapply_kernel(const ushort_t* __restrict__ hpre, const float* __restrict__ stats,
                                 const float* __restrict__ gamma, const float* __restrict__ beta,
                                 float invN, const int* __restrict__ batch,
                                 float* __restrict__ pooled, float* __restrict__ pcnt, int N) {
  __shared__ float cf[128];
  int t = threadIdx.x;
  if (t < 64) {
    float mu = stats[t] * invN;
    float var = fmaxf(stats[D + t] * invN - mu * mu, 0.f);
    float rs = rsqrtf(var + 1e-5f);
    float sc = gamma[t] * rs;
    cf[t] = sc;
    cf[64 + t] = beta[t] - mu * sc;
  }
  __syncthreads();
  int lane = t & 63;
  int wid = (blockIdx.x * blockDim.x + t) >> 6;
  int nw = (gridDim.x * blockDim.x) >> 6;
  float sc = cf[lane], sh = cf[64 + lane];
  for (int n = wid; n < N; n += nw) {
    int b = batch[n];
    float v = bf2f(hpre[(size_t)n * D + lane]) * sc + sh;
    v = v > 0.f ? v : __expf(v) - 1.f;
    atomicAdd(&pooled[(size_t)b * D + lane], v);
    if (lane == 0) atomicAdd(&pcnt[b], 1.0f);
  }
}

// ---------------- head ----------------
__global__ void head_kernel(const float* __restrict__ pooled, const float* __restrict__ pcnt,
                            const float* __restrict__ Wout, const float* __restrict__ bout,
                            float* __restrict__ outp, int G) {
  int idx = blockIdx.x * blockDim.x + threadIdx.x;
  if (idx >= G * 16) return;
  int g = idx >> 4;
  int o = idx & 15;
  float inv = 1.0f / fmaxf(pcnt[g], 1.0f);
  float acc = 0.f;
#pragma unroll
  for (int i = 0; i < D; ++i) acc += pooled[(size_t)g * D + i] * Wout[i * 16 + o];
  outp[idx] = acc * inv + bout[o];
}

extern "C" void kernel_launch(void* const* d_in, const int* in_sizes, int n_in,
                              void* d_out, int out_size, void* d_ws, size_t ws_size,
                              hipStream_t stream) {
  (void)n_in; (void)ws_size;
  const float* x      = (const float*)d_in[0];
  const int*   edge   = (const int*)d_in[1];
  const int*   batch  = (const int*)d_in[2];
  const float* W0     = (const float*)d_in[3];
  const float* b0     = (const float*)d_in[4];
  const float* Wl     = (const float*)d_in[5];
  const float* bl     = (const float*)d_in[6];
  const float* Wr     = (const float*)d_in[7];
  const float* W2a    = (const float*)d_in[8];
  const float* b2a    = (const float*)d_in[9];
  const float* W2b    = (const float*)d_in[10];
  const float* b2b    = (const float*)d_in[11];
  const float* Wrel   = (const float*)d_in[12];
  const float* brel   = (const float*)d_in[13];
  const float* Wroot  = (const float*)d_in[14];
  const float* gammas = (const float*)d_in[15];
  const float* betas  = (const float*)d_in[16];
  const float* Wout   = (const float*)d_in[17];
  const float* bout   = (const float*)d_in[18];
  float* out = (float*)d_out;

  int N = in_sizes[0] / D;
  int E = in_sizes[1] / 2;
  int G = out_size / 16;
  const int* src = edge;
  const int* dst = edge + E;

  float* ws = (float*)d_ws;
  float* deg  = ws;                          // N
  float* stats = deg + N;                    // 4 layers x 128
  float* pooled = stats + 4 * 2 * D;         // G*64
  float* pcnt   = pooled + (size_t)G * D;    // G
  int* hist    = (int*)(pcnt + G);           // N ints (also cursor)
  int* rowptr  = hist + N;                   // N+1 ints
  int* csr_src = rowptr + N + 1;             // E ints
  int* blocksum = csr_src + E;               // 256 ints
  int* blockoff = blocksum + NB_SCAN;        // 256 ints
  ushort_t* hb   = (ushort_t*)(blockoff + NB_SCAN);  // N*64 bf16
  ushort_t* aggb = hb + (size_t)N * D;                // N*64 bf16
  ushort_t* zb   = aggb + (size_t)N * D;              // N*64 bf16 (GIN z)
  ushort_t* hpb  = zb + (size_t)N * D;                // N*64 bf16 (h_pre)
  ushort_t* wpB  = hpb + (size_t)N * D;               // 7 x 4096 packed weights
  ushort_t* wp0   = wpB + 0 * 4096;
  ushort_t* wpl   = wpB + 1 * 4096;
  ushort_t* wpr   = wpB + 2 * 4096;
  ushort_t* wp2a  = wpB + 3 * 4096;
  ushort_t* wp2b  = wpB + 4 * 4096;
  ushort_t* wprel = wpB + 5 * 4096;
  ushort_t* wproot = wpB + 6 * 4096;

  int total4 = N * D / 4;
  int gather_blocks = (N * 64 + 255) / 256;
  if (gather_blocks > 8192) gather_blocks = 8192;
  int mmx_blocks = 2048;
  float invN = 1.0f / (float)N;

  // ---- build CSR ----
  hipMemsetAsync(hist, 0, N * sizeof(int), stream);
  hipMemsetAsync(stats, 0, 4 * 2 * D * sizeof(float), stream);
  hist_kernel<<<1024, 256, 0, stream>>>(dst, hist, E);
  scanA_kernel<<<NB_SCAN, 256, 0, stream>>>(hist, blocksum, N);
  scanB_kernel<<<1, NB_SCAN, 0, stream>>>(blocksum, blockoff, rowptr + N);
  scanC_kernel<<<NB_SCAN, 256, 0, stream>>>(hist, blockoff, rowptr, deg, N);  // zeroes hist in-pass
  fillp_kernel<<<1024, 256, 0, stream>>>(src, dst, rowptr, hist, csr_src, E, N);

  // ---- pack weights (single launch) ----
  packw7_kernel<<<112, 256, 0, stream>>>(W0, Wl, Wr, W2a, W2b, Wrel, Wroot, wpB);

  // ---- layer 0: custom_mp: (mean agg x)@W0 + masked b0 ----
  cvt_kernel<<<2048, 256, 0, stream>>>(x, hb, total4);
  gatherb_kernel<<<gather_blocks, 256, 0, stream>>>(hb, rowptr, csr_src, aggb, N);
  mmx_kernel<0, 1, 1, 0, 1, 1><<<mmx_blocks, 256, 0, stream>>>(
      aggb, nullptr, wp0, nullptr, b0, deg, nullptr, hpb, stats + 0 * 128, N);
  apply_kernel<<<2048, 256, 0, stream>>>(hpb, stats + 0 * 128, gammas + 0 * D, betas + 0 * D, invN, hb, total4);

  // ---- layer 1: SAGE: (mean agg)@Wl + bl + h@Wr ----
  gatherb_kernel<<<gather_blocks, 256, 0, stream>>>(hb, rowptr, csr_src, aggb, N);
  mmx_kernel<1, 1, 0, 0, 1, 1><<<mmx_blocks, 256, 0, stream>>>(
      aggb, hb, wpl, wpr, bl, deg, nullptr, hpb, stats + 1 * 128, N);
  apply_kernel<<<2048, 256, 0, stream>>>(hpb, stats + 1 * 128, gammas + 1 * D, betas + 1 * D, invN, hb, total4);

  // ---- layer 2: GIN: z = relu(s@W2a + h@W2a + b2a); h_pre = z@W2b + b2b ----
  gatherb_kernel<<<gather_blocks, 256, 0, stream>>>(hb, rowptr, csr_src, aggb, N);
  mmx_kernel<1, 0, 0, 1, 0, 1><<<mmx_blocks, 256, 0, stream>>>(
      aggb, hb, wp2a, wp2a, b2a, deg, nullptr, zb, nullptr, N);
  mmx_kernel<0, 0, 0, 0, 1, 1><<<mmx_blocks, 256, 0, stream>>>(
      zb, nullptr, wp2b, nullptr, b2b, deg, nullptr, hpb, stats + 2 * 128, N);
  apply_kernel<<<2048, 256, 0, stream>>>(hpb, stats + 2 * 128, gammas + 2 * D, betas + 2 * D, invN, hb, total4);

  // ---- layer 3: GraphConv: (sum agg)@Wrel + brel + h@Wroot ----
  gatherb_kernel<<<gather_blocks, 256, 0, stream>>>(hb, rowptr, csr_src, aggb, N);
  mmx_kernel<1, 0, 0, 0, 1, 1><<<mmx_blocks, 256, 0, stream>>>(
      aggb, hb, wprel, wproot, brel, deg, nullptr, hpb, stats + 3 * 128, N);

  // ---- pool (BN+ELU fused) + head ----
  hipMemsetAsync(pooled, 0, (size_t)G * D * sizeof(float), stream);
  hipMemsetAsync(pcnt, 0, G * sizeof(float), stream);
  poolapply_kernel<<<1024, 256, 0, stream>>>(hpb, stats + 3 * 128, gammas + 3 * D, betas + 3 * D,
                                             invN, batch, pooled, pcnt, N);
  head_kernel<<<(G * 16 + 255) / 256, 256, 0, stream>>>(pooled, pcnt, Wout, bout, out, G);
}

// Round 20
// 596.662 us; speedup vs baseline: 1.1369x; 1.1369x over previous
//
#include <hip/hip_runtime.h>
#include <math.h>

#define D 64
#define NB_SCAN 256

typedef unsigned short ushort_t;
typedef __attribute__((ext_vector_type(8))) short bf16x8;
typedef __attribute__((ext_vector_type(4))) float f32x4;

__device__ __forceinline__ ushort_t f2bf(float f) {
  unsigned int u = __float_as_uint(f);
  unsigned int r = (u + 0x7fffu + ((u >> 16) & 1u)) >> 16;  // RNE
  return (ushort_t)r;
}

__device__ __forceinline__ float bf2f(ushort_t b) {
  return __uint_as_float((unsigned int)b << 16);
}

// ---------------- degree histogram (int) ----------------
__global__ void hist_kernel(const int* __restrict__ dst, int* __restrict__ hist, int E) {
  int i = blockIdx.x * blockDim.x + threadIdx.x;
  int stride = gridDim.x * blockDim.x;
  for (int e = i; e < E; e += stride) atomicAdd(&hist[dst[e]], 1);
}

// ---------------- 3-pass scan ----------------
__global__ void scanA_kernel(const int* __restrict__ hist, int* __restrict__ blocksum, int N) {
  __shared__ int red[256];
  int b = blockIdx.x, t = threadIdx.x;
  int chunk = (N + NB_SCAN - 1) / NB_SCAN;
  int beg = b * chunk;
  int end = min(beg + chunk, N);
  int s = 0;
  for (int i = beg + t; i < end; i += 256) s += hist[i];
  red[t] = s;
  __syncthreads();
  for (int off = 128; off > 0; off >>= 1) {
    if (t < off) red[t] += red[t + off];
    __syncthreads();
  }
  if (t == 0) blocksum[b] = red[0];
}

__global__ void scanB_kernel(const int* __restrict__ blocksum, int* __restrict__ blockoff,
                             int* __restrict__ rowptr_last) {
  __shared__ int sm[NB_SCAN];
  int t = threadIdx.x;
  sm[t] = blocksum[t];
  __syncthreads();
  for (int off = 1; off < NB_SCAN; off <<= 1) {
    int v = (t >= off) ? sm[t - off] : 0;
    __syncthreads();
    sm[t] += v;
    __syncthreads();
  }
  blockoff[t] = (t == 0) ? 0 : sm[t - 1];
  if (t == NB_SCAN - 1) rowptr_last[0] = sm[t];
}

__global__ void scanC_kernel(const int* __restrict__ hist, const int* __restrict__ blockoff,
                             int* __restrict__ rowptr, float* __restrict__ degf, int N) {
  __shared__ int sm[256];
  int b = blockIdx.x, t = threadIdx.x;
  int chunk = (N + NB_SCAN - 1) / NB_SCAN;
  int beg = b * chunk;
  int end = min(beg + chunk, N);
  int sub = (chunk + 255) / 256;
  int mybeg = beg + t * sub;
  int myend = min(mybeg + sub, end);
  int s = 0;
  for (int i = mybeg; i < myend; ++i) s += hist[i];
  sm[t] = s;
  __syncthreads();
  for (int off = 1; off < 256; off <<= 1) {
    int v = (t >= off) ? sm[t - off] : 0;
    __syncthreads();
    sm[t] += v;
    __syncthreads();
  }
  int run = blockoff[b] + ((t == 0) ? 0 : sm[t - 1]);
  for (int i = mybeg; i < myend; ++i) {
    int h = hist[i];
    rowptr[i] = run;
    degf[i] = (float)h;
    run += h;
  }
}

// ---------------- range-partitioned XCD-affine CSR fill (plain loads) ----------------
__global__ void fillp_kernel(const int* __restrict__ src, const int* __restrict__ dst,
                             const int* __restrict__ rowptr, int* __restrict__ cursor,
                             int* __restrict__ csr_src, int E, int N) {
  int r = blockIdx.x & 7;
  int c = blockIdx.x >> 3;
  int nchunk = gridDim.x >> 3;
  int lo = (r * N) >> 3;
  int hi = ((r + 1) * N) >> 3;
  int per = (E + nchunk - 1) / nchunk;
  int beg = c * per;
  int end = min(beg + per, E);
  for (int e = beg + (int)threadIdx.x; e < end; e += (int)blockDim.x) {
    int d = dst[e];
    if (d >= lo && d < hi) {
      int pos = atomicAdd(&cursor[d], 1);
      csr_src[rowptr[d] + pos] = src[e];
    }
  }
}

// ---------------- f32 -> bf16 convert (vectorized) ----------------
__global__ void cvt_kernel(const float* __restrict__ in, ushort_t* __restrict__ outb, int total4) {
  int i = blockIdx.x * blockDim.x + threadIdx.x;
  int stride = gridDim.x * blockDim.x;
  const float4* in4 = (const float4*)in;
  for (int idx = i; idx < total4; idx += stride) {
    float4 v = in4[idx];
    ushort4 u;
    u.x = f2bf(v.x); u.y = f2bf(v.y); u.z = f2bf(v.z); u.w = f2bf(v.w);
    ((ushort4*)outb)[idx] = u;
  }
}

// ---------------- pack W[64][64] f32 -> bf16 B-fragment order ----------------
__global__ void packw_kernel(const float* __restrict__ W, ushort_t* __restrict__ Wp) {
  int idx = blockIdx.x * blockDim.x + threadIdx.x;
  if (idx >= 4096) return;
  int i = idx & 7;
  int lane = (idx >> 3) & 63;
  int ct = (idx >> 9) & 3;
  int kt = idx >> 11;
  int k = kt * 32 + ((lane >> 4) << 3) + i;
  int c = (ct << 4) + (lane & 15);
  Wp[idx] = f2bf(W[k * D + c]);
}

// ------- bf16 gather-sum -> bf16 agg: uint4 loads, 8 edges/step (lane = e8*8 + c8) -------
#define ACC8(p) { \
  a0 += __uint_as_float(p.x << 16); a1 += __uint_as_float(p.x & 0xffff0000u); \
  a2 += __uint_as_float(p.y << 16); a3 += __uint_as_float(p.y & 0xffff0000u); \
  a4 += __uint_as_float(p.z << 16); a5 += __uint_as_float(p.z & 0xffff0000u); \
  a6 += __uint_as_float(p.w << 16); a7 += __uint_as_float(p.w & 0xffff0000u); }

#define GSTEP8(j) { int i0 = 8 * (j) + e8; \
  int ia = __shfl(myidx, i0 & 63); \
  uint4 p = *(const uint4*)(hb + (size_t)ia * D + (c8 << 3)); \
  if (i0 >= cnt) { p.x = 0u; p.y = 0u; p.z = 0u; p.w = 0u; } \
  ACC8(p) }

__global__ void gatherb_kernel(const ushort_t* __restrict__ hb, const int* __restrict__ rowptr,
                               const int* __restrict__ csr_src, ushort_t* __restrict__ aggb, int N) {
  int lane = threadIdx.x & 63;
  int wid = (blockIdx.x * blockDim.x + threadIdx.x) >> 6;
  int nw = (gridDim.x * blockDim.x) >> 6;
  int e8 = lane >> 3;
  int c8 = lane & 7;
  for (int n = wid; n < N; n += nw) {
    int beg = __builtin_amdgcn_readfirstlane(rowptr[n]);
    int end = __builtin_amdgcn_readfirstlane(rowptr[n + 1]);
    int cnt = end - beg;
    float a0 = 0.f, a1 = 0.f, a2 = 0.f, a3 = 0.f, a4 = 0.f, a5 = 0.f, a6 = 0.f, a7 = 0.f;
    if (cnt <= 64) {
      int myidx = (lane < cnt) ? csr_src[beg + lane] : 0;
      if (cnt <= 16) {
        GSTEP8(0) GSTEP8(1)
      } else if (cnt <= 32) {
        GSTEP8(0) GSTEP8(1) GSTEP8(2) GSTEP8(3)
      } else {
        GSTEP8(0) GSTEP8(1) GSTEP8(2) GSTEP8(3)
        GSTEP8(4) GSTEP8(5) GSTEP8(6) GSTEP8(7)
      }
    } else {
      for (int k = beg; k < end; k += 64) {
        int myidx = (k + lane < end) ? csr_src[k + lane] : 0;
        int cnt2 = end - k; if (cnt2 > 64) cnt2 = 64;
        int cnt = cnt2;
#pragma unroll
        for (int j = 0; j < 8; ++j) {
          if (8 * j < cnt) { GSTEP8(j) }
        }
      }
    }
    a0 += __shfl_xor(a0, 8); a0 += __shfl_xor(a0, 16); a0 += __shfl_xor(a0, 32);
    a1 += __shfl_xor(a1, 8); a1 += __shfl_xor(a1, 16); a1 += __shfl_xor(a1, 32);
    a2 += __shfl_xor(a2, 8); a2 += __shfl_xor(a2, 16); a2 += __shfl_xor(a2, 32);
    a3 += __shfl_xor(a3, 8); a3 += __shfl_xor(a3, 16); a3 += __shfl_xor(a3, 32);
    a4 += __shfl_xor(a4, 8); a4 += __shfl_xor(a4, 16); a4 += __shfl_xor(a4, 32);
    a5 += __shfl_xor(a5, 8); a5 += __shfl_xor(a5, 16); a5 += __shfl_xor(a5, 32);
    a6 += __shfl_xor(a6, 8); a6 += __shfl_xor(a6, 16); a6 += __shfl_xor(a6, 32);
    a7 += __shfl_xor(a7, 8); a7 += __shfl_xor(a7, 16); a7 += __shfl_xor(a7, 32);
    if (lane < 8) {
      uint4 u;
      u.x = ((unsigned int)f2bf(a1) << 16) | (unsigned int)f2bf(a0);
      u.y = ((unsigned int)f2bf(a3) << 16) | (unsigned int)f2bf(a2);
      u.z = ((unsigned int)f2bf(a5) << 16) | (unsigned int)f2bf(a4);
      u.w = ((unsigned int)f2bf(a7) << 16) | (unsigned int)f2bf(a6);
      *(uint4*)(aggb + (size_t)n * D + (c8 << 3)) = u;
    }
  }
}

// ======== MFMA matmul: out = A1@W1 (scaled) [+ A2@W2] + bias(masked) ========
template <int DUAL, int SCALEA, int MASKB, int RELU, int STATS, int OUTBF>
__global__ __launch_bounds__(256, 4)
void mmx_kernel(const ushort_t* __restrict__ A1, const ushort_t* __restrict__ A2,
                const ushort_t* __restrict__ Wp1, const ushort_t* __restrict__ Wp2,
                const float* __restrict__ bias, const float* __restrict__ deg,
                float* __restrict__ outf, ushort_t* __restrict__ outb,
                float* __restrict__ stats, int N) {
  int lane = threadIdx.x & 63;
  int wv = (blockIdx.x * blockDim.x + threadIdx.x) >> 6;
  int nw = (gridDim.x * blockDim.x) >> 6;
  int T = (N + 15) >> 4;
  int lr = lane & 15;
  int lk = lane >> 4;
  float s1[4] = {0.f, 0.f, 0.f, 0.f};
  float s2[4] = {0.f, 0.f, 0.f, 0.f};

  for (int t = wv; t < T; t += nw) {
    int r0 = t << 4;
    int rowA = r0 + lr;
    if (rowA >= N) rowA = N - 1;
    const ushort_t* pa = A1 + (size_t)rowA * D + (lk << 3);
    bf16x8 a1k0 = *(const bf16x8*)(pa);
    bf16x8 a1k1 = *(const bf16x8*)(pa + 32);
    bf16x8 a2k0{}, a2k1{};
    if constexpr (DUAL) {
      const ushort_t* ph = A2 + (size_t)rowA * D + (lk << 3);
      a2k0 = *(const bf16x8*)(ph);
      a2k1 = *(const bf16x8*)(ph + 32);
    }
    float invd[4], msk[4];
#pragma unroll
    for (int rg = 0; rg < 4; ++rg) {
      if constexpr (SCALEA || MASKB) {
        int rr = r0 + (lk << 2) + rg;
        if (rr >= N) rr = N - 1;
        float dv = deg[rr];
        invd[rg] = 1.0f / fmaxf(dv, 1.0f);
        msk[rg] = (dv > 0.f) ? 1.f : 0.f;
      } else {
        invd[rg] = 1.f; msk[rg] = 1.f;
      }
    }

#pragma unroll
    for (int ct = 0; ct < 4; ++ct) {
      bf16x8 w1k0 = *(const bf16x8*)(Wp1 + (((0 * 4 + ct) * 64 + lane) << 3));
      bf16x8 w1k1 = *(const bf16x8*)(Wp1 + (((1 * 4 + ct) * 64 + lane) << 3));
      f32x4 accA = {0.f, 0.f, 0.f, 0.f};
      accA = __builtin_amdgcn_mfma_f32_16x16x32_bf16(a1k0, w1k0, accA, 0, 0, 0);
      accA = __builtin_amdgcn_mfma_f32_16x16x32_bf16(a1k1, w1k1, accA, 0, 0, 0);
      f32x4 accH = {0.f, 0.f, 0.f, 0.f};
      if constexpr (DUAL) {
        bf16x8 w2k0 = *(const bf16x8*)(Wp2 + (((0 * 4 + ct) * 64 + lane) << 3));
        bf16x8 w2k1 = *(const bf16x8*)(Wp2 + (((1 * 4 + ct) * 64 + lane) << 3));
        accH = __builtin_amdgcn_mfma_f32_16x16x32_bf16(a2k0, w2k0, accH, 0, 0, 0);
        accH = __builtin_amdgcn_mfma_f32_16x16x32_bf16(a2k1, w2k1, accH, 0, 0, 0);
      }
      float bj = bias[(ct << 4) + lr];
#pragma unroll
      for (int rg = 0; rg < 4; ++rg) {
        int row = r0 + (lk << 2) + rg;
        float v = accA[rg];
        if constexpr (SCALEA) v *= invd[rg];
        if constexpr (DUAL) v += accH[rg];
        if constexpr (MASKB) v += bj * msk[rg]; else v += bj;
        if constexpr (RELU) v = fmaxf(v, 0.f);
        if (row < N) {
          int col = (ct << 4) + lr;
          if constexpr (OUTBF) outb[(size_t)row * D + col] = f2bf(v);
          else outf[(size_t)row * D + col] = v;
          if constexpr (STATS) { s1[ct] += v; s2[ct] += v * v; }
        }
      }
    }
  }

  if constexpr (STATS) {
    __shared__ float red[2][4][256];
#pragma unroll
    for (int ct = 0; ct < 4; ++ct) {
      red[0][ct][threadIdx.x] = s1[ct];
      red[1][ct][threadIdx.x] = s2[ct];
    }
    __syncthreads();
    int tt = threadIdx.x;
    if (tt < 64) {
      int ct = tt >> 4, base = tt & 15;
      float t1 = 0.f, t2 = 0.f;
      for (int i = 0; i < 16; ++i) {
        t1 += red[0][ct][base + i * 16];
        t2 += red[1][ct][base + i * 16];
      }
      atomicAdd(&stats[tt], t1);
      atomicAdd(&stats[D + tt], t2);
    }
  }
}

// ---------------- BN apply + ELU (bn_coef fused in-block): bf16 h_pre -> bf16 hb ----------------
__global__ void apply_kernel(const ushort_t* __restrict__ hpre, const float* __restrict__ stats,
                             const float* __restrict__ gamma, const float* __restrict__ beta,
                             float invN, ushort_t* __restrict__ hb, int total4) {
  __shared__ float cf[128];
  int t = threadIdx.x;
  if (t < 64) {
    float mu = stats[t] * invN;
    float var = fmaxf(stats[D + t] * invN - mu * mu, 0.f);
    float rs = rsqrtf(var + 1e-5f);
    float sc = gamma[t] * rs;
    cf[t] = sc;
    cf[64 + t] = beta[t] - mu * sc;
  }
  __syncthreads();
  int i = blockIdx.x * blockDim.x + t;
  int stride = gridDim.x * blockDim.x;
  const ushort4* in4 = (const ushort4*)hpre;
  for (int idx = i; idx < total4; idx += stride) {
    int col4 = idx & 15;
    float4 sc = *(const float4*)(cf + col4 * 4);
    float4 sh = *(const float4*)(cf + 64 + col4 * 4);
    ushort4 vu = in4[idx];
    float4 r;
    r.x = bf2f(vu.x) * sc.x + sh.x;
    r.y = bf2f(vu.y) * sc.y + sh.y;
    r.z = bf2f(vu.z) * sc.z + sh.z;
    r.w = bf2f(vu.w) * sc.w + sh.w;
    r.x = r.x > 0.f ? r.x : __expf(r.x) - 1.f;
    r.y = r.y > 0.f ? r.y : __expf(r.y) - 1.f;
    r.z = r.z > 0.f ? r.z : __expf(r.z) - 1.f;
    r.w = r.w > 0.f ? r.w : __expf(r.w) - 1.f;
    ushort4 u;
    u.x = f2bf(r.x); u.y = f2bf(r.y); u.z = f2bf(r.z); u.w = f2bf(r.w);
    ((ushort4*)hb)[idx] = u;
  }
}

// ---------------- global mean pool with fused BN+ELU (reads bf16 h_pre) ----------------
__global__ void poolapply_kernel(const ushort_t* __restrict__ hpre, const float* __restrict__ stats,
                                 const float* __restrict__ gamma, const float* __restrict__ beta,
                                 float invN, const int* __restrict__ batch,
                                 float* __restrict__ pooled, float* __restrict__ pcnt, int N) {
  __shared__ float cf[128];
  int t = threadIdx.x;
  if (t < 64) {
    float mu = stats[t] * invN;
    float var = fmaxf(stats[D + t] * invN - mu * mu, 0.f);
    float rs = rsqrtf(var + 1e-5f);
    float sc = gamma[t] * rs;
    cf[t] = sc;
    cf[64 + t] = beta[t] - mu * sc;
  }
  __syncthreads();
  int lane = t & 63;
  int wid = (blockIdx.x * blockDim.x + t) >> 6;
  int nw = (gridDim.x * blockDim.x) >> 6;
  float sc = cf[lane], sh = cf[64 + lane];
  for (int n = wid; n < N; n += nw) {
    int b = batch[n];
    float v = bf2f(hpre[(size_t)n * D + lane]) * sc + sh;
    v = v > 0.f ? v : __expf(v) - 1.f;
    atomicAdd(&pooled[(size_t)b * D + lane], v);
    if (lane == 0) atomicAdd(&pcnt[b], 1.0f);
  }
}

// ---------------- head ----------------
__global__ void head_kernel(const float* __restrict__ pooled, const float* __restrict__ pcnt,
                            const float* __restrict__ Wout, const float* __restrict__ bout,
                            float* __restrict__ outp, int G) {
  int idx = blockIdx.x * blockDim.x + threadIdx.x;
  if (idx >= G * 16) return;
  int g = idx >> 4;
  int o = idx & 15;
  float inv = 1.0f / fmaxf(pcnt[g], 1.0f);
  float acc = 0.f;
#pragma unroll
  for (int i = 0; i < D; ++i) acc += pooled[(size_t)g * D + i] * Wout[i * 16 + o];
  outp[idx] = acc * inv + bout[o];
}

extern "C" void kernel_launch(void* const* d_in, const int* in_sizes, int n_in,
                              void* d_out, int out_size, void* d_ws, size_t ws_size,
                              hipStream_t stream) {
  (void)n_in; (void)ws_size;
  const float* x      = (const float*)d_in[0];
  const int*   edge   = (const int*)d_in[1];
  const int*   batch  = (const int*)d_in[2];
  const float* W0     = (const float*)d_in[3];
  const float* b0     = (const float*)d_in[4];
  const float* Wl     = (const float*)d_in[5];
  const float* bl     = (const float*)d_in[6];
  const float* Wr     = (const float*)d_in[7];
  const float* W2a    = (const float*)d_in[8];
  const float* b2a    = (const float*)d_in[9];
  const float* W2b    = (const float*)d_in[10];
  const float* b2b    = (const float*)d_in[11];
  const float* Wrel   = (const float*)d_in[12];
  const float* brel   = (const float*)d_in[13];
  const float* Wroot  = (const float*)d_in[14];
  const float* gammas = (const float*)d_in[15];
  const float* betas  = (const float*)d_in[16];
  const float* Wout   = (const float*)d_in[17];
  const float* bout   = (const float*)d_in[18];
  float* out = (float*)d_out;

  int N = in_sizes[0] / D;
  int E = in_sizes[1] / 2;
  int G = out_size / 16;
  const int* src = edge;
  const int* dst = edge + E;

  float* ws = (float*)d_ws;
  float* deg  = ws;                          // N
  float* stats = deg + N;                    // 4 layers x 128
  float* pooled = stats + 4 * 2 * D;         // G*64
  float* pcnt   = pooled + (size_t)G * D;    // G
  int* hist    = (int*)(pcnt + G);           // N ints (also cursor)
  int* rowptr  = hist + N;                   // N+1 ints
  int* csr_src = rowptr + N + 1;             // E ints
  int* blocksum = csr_src + E;               // 256 ints
  int* blockoff = blocksum + NB_SCAN;        // 256 ints
  ushort_t* hb   = (ushort_t*)(blockoff + NB_SCAN);  // N*64 bf16
  ushort_t* aggb = hb + (size_t)N * D;                // N*64 bf16
  ushort_t* zb   = aggb + (size_t)N * D;              // N*64 bf16 (GIN z)
  ushort_t* hpb  = zb + (size_t)N * D;                // N*64 bf16 (h_pre)
  ushort_t* wp0   = hpb + (size_t)N * D;              // 7 x 4096 packed weights
  ushort_t* wpl   = wp0 + 4096;
  ushort_t* wpr   = wpl + 4096;
  ushort_t* wp2a  = wpr + 4096;
  ushort_t* wp2b  = wp2a + 4096;
  ushort_t* wprel = wp2b + 4096;
  ushort_t* wproot = wprel + 4096;

  int total4 = N * D / 4;
  int gather_blocks = (N * 64 + 255) / 256;
  if (gather_blocks > 8192) gather_blocks = 8192;
  int mmx_blocks = 1024;
  float invN = 1.0f / (float)N;

  // ---- build CSR ----
  hipMemsetAsync(hist, 0, N * sizeof(int), stream);
  hipMemsetAsync(stats, 0, 4 * 2 * D * sizeof(float), stream);
  hist_kernel<<<1024, 256, 0, stream>>>(dst, hist, E);
  scanA_kernel<<<NB_SCAN, 256, 0, stream>>>(hist, blocksum, N);
  scanB_kernel<<<1, NB_SCAN, 0, stream>>>(blocksum, blockoff, rowptr + N);
  scanC_kernel<<<NB_SCAN, 256, 0, stream>>>(hist, blockoff, rowptr, deg, N);
  hipMemsetAsync(hist, 0, N * sizeof(int), stream);  // reuse as cursor
  fillp_kernel<<<1024, 256, 0, stream>>>(src, dst, rowptr, hist, csr_src, E, N);

  // ---- pack weights (bf16 fragment order) ----
  packw_kernel<<<16, 256, 0, stream>>>(W0, wp0);
  packw_kernel<<<16, 256, 0, stream>>>(Wl, wpl);
  packw_kernel<<<16, 256, 0, stream>>>(Wr, wpr);
  packw_kernel<<<16, 256, 0, stream>>>(W2a, wp2a);
  packw_kernel<<<16, 256, 0, stream>>>(W2b, wp2b);
  packw_kernel<<<16, 256, 0, stream>>>(Wrel, wprel);
  packw_kernel<<<16, 256, 0, stream>>>(Wroot, wproot);

  // ---- layer 0: custom_mp: (mean agg x)@W0 + masked b0 ----
  cvt_kernel<<<2048, 256, 0, stream>>>(x, hb, total4);
  gatherb_kernel<<<gather_blocks, 256, 0, stream>>>(hb, rowptr, csr_src, aggb, N);
  mmx_kernel<0, 1, 1, 0, 1, 1><<<mmx_blocks, 256, 0, stream>>>(
      aggb, nullptr, wp0, nullptr, b0, deg, nullptr, hpb, stats + 0 * 128, N);
  apply_kernel<<<2048, 256, 0, stream>>>(hpb, stats + 0 * 128, gammas + 0 * D, betas + 0 * D, invN, hb, total4);

  // ---- layer 1: SAGE: (mean agg)@Wl + bl + h@Wr ----
  gatherb_kernel<<<gather_blocks, 256, 0, stream>>>(hb, rowptr, csr_src, aggb, N);
  mmx_kernel<1, 1, 0, 0, 1, 1><<<mmx_blocks, 256, 0, stream>>>(
      aggb, hb, wpl, wpr, bl, deg, nullptr, hpb, stats + 1 * 128, N);
  apply_kernel<<<2048, 256, 0, stream>>>(hpb, stats + 1 * 128, gammas + 1 * D, betas + 1 * D, invN, hb, total4);

  // ---- layer 2: GIN: z = relu(s@W2a + h@W2a + b2a); h_pre = z@W2b + b2b ----
  gatherb_kernel<<<gather_blocks, 256, 0, stream>>>(hb, rowptr, csr_src, aggb, N);
  mmx_kernel<1, 0, 0, 1, 0, 1><<<mmx_blocks, 256, 0, stream>>>(
      aggb, hb, wp2a, wp2a, b2a, deg, nullptr, zb, nullptr, N);
  mmx_kernel<0, 0, 0, 0, 1, 1><<<mmx_blocks, 256, 0, stream>>>(
      zb, nullptr, wp2b, nullptr, b2b, deg, nullptr, hpb, stats + 2 * 128, N);
  apply_kernel<<<2048, 256, 0, stream>>>(hpb, stats + 2 * 128, gammas + 2 * D, betas + 2 * D, invN, hb, total4);

  // ---- layer 3: GraphConv: (sum agg)@Wrel + brel + h@Wroot ----
  gatherb_kernel<<<gather_blocks, 256, 0, stream>>>(hb, rowptr, csr_src, aggb, N);
  mmx_kernel<1, 0, 0, 0, 1, 1><<<mmx_blocks, 256, 0, stream>>>(
      aggb, hb, wprel, wproot, brel, deg, nullptr, hpb, stats + 3 * 128, N);

  // ---- pool (BN+ELU fused) + head ----
  hipMemsetAsync(pooled, 0, (size_t)G * D * sizeof(float), stream);
  hipMemsetAsync(pcnt, 0, G * sizeof(float), stream);
  poolapply_kernel<<<1024, 256, 0, stream>>>(hpb, stats + 3 * 128, gammas + 3 * D, betas + 3 * D,
                                             invN, batch, pooled, pcnt, N);
  head_kernel<<<(G * 16 + 255) / 256, 256, 0, stream>>>(pooled, pcnt, Wout, bout, out, G);
}